// Round 10
// baseline (342.510 us; speedup 1.0000x reference)
//
#include <hip/hip_runtime.h>
#include <hip/hip_bf16.h>
#include <math.h>

#define T_TOK 2048
#define HDIM  2048
#define IDIM  1408
#define NG    2816          // 2*IDIM
#define NEXP  8
#define NPAIR (T_TOK*2)
#define RPAD  5120          // 4096 rows + per-expert pad-to-128 (max 5112)

typedef __attribute__((ext_vector_type(4))) float  f32x4;
typedef __attribute__((ext_vector_type(4))) short  s16x4;
typedef __attribute__((ext_vector_type(8))) short  s16x8;
typedef __attribute__((ext_vector_type(8))) __bf16 bf16x8;

__device__ __forceinline__ short f2bf(float f) {
  union { float f; unsigned u; } v; v.f = f;
  unsigned r = v.u + 0x7FFFu + ((v.u >> 16) & 1u);   // RNE
  return (short)(r >> 16);
}

__device__ __forceinline__ float bf2f(short s) {
  union { unsigned u; float f; } v; v.u = ((unsigned)(unsigned short)s) << 16;
  return v.f;
}

__device__ __forceinline__ void gload_lds16(const void* g, void* l) {
  __builtin_amdgcn_global_load_lds((const __attribute__((address_space(1))) unsigned int*)g,
                                   (__attribute__((address_space(3))) unsigned int*)l,
                                   16, 0, 0);
}

// ---------------- router ----------------
__global__ void router_kernel(const float* __restrict__ hs, const float* __restrict__ rw,
                              int* __restrict__ pair_e, float* __restrict__ pair_w,
                              int* __restrict__ pair_pos, int* __restrict__ counts) {
  int wid = threadIdx.x >> 6, lane = threadIdx.x & 63;
  int t = blockIdx.x * 4 + wid;
  float acc[NEXP];
#pragma unroll
  for (int e = 0; e < NEXP; e++) acc[e] = 0.f;
  const float* h = hs + (size_t)t * HDIM;
  for (int k = lane; k < HDIM; k += 64) {
    float x = h[k];
    f32x4 w0 = *(const f32x4*)(rw + (size_t)k * NEXP);
    f32x4 w1 = *(const f32x4*)(rw + (size_t)k * NEXP + 4);
#pragma unroll
    for (int e = 0; e < 4; e++) { acc[e] += x * w0[e]; acc[e + 4] += x * w1[e]; }
  }
#pragma unroll
  for (int e = 0; e < NEXP; e++)
#pragma unroll
    for (int off = 32; off > 0; off >>= 1)
      acc[e] += __shfl_xor(acc[e], off, 64);
  if (lane == 0) {
    int i1 = 0; float v1 = acc[0];
#pragma unroll
    for (int e = 1; e < NEXP; e++) if (acc[e] > v1) { v1 = acc[e]; i1 = e; }
    int i2 = -1; float v2 = -3.4e38f;
#pragma unroll
    for (int e = 0; e < NEXP; e++) if (e != i1 && acc[e] > v2) { v2 = acc[e]; i2 = e; }
    float w2 = 1.f / (1.f + expf(v1 - v2));
    float w1 = 1.f - w2;
    int p1 = atomicAdd(&counts[i1], 1);
    int p2 = atomicAdd(&counts[i2], 1);
    pair_e[2*t]   = i1; pair_w[2*t]   = w1; pair_pos[2*t]   = p1;
    pair_e[2*t+1] = i2; pair_w[2*t+1] = w2; pair_pos[2*t+1] = p2;
  }
}

__global__ void prefix_kernel(const int* __restrict__ counts, int* __restrict__ offs) {
  if (threadIdx.x == 0) {
    int s = 0;
    for (int e = 0; e < NEXP; e++) { offs[e] = s; s += (counts[e] + 127) & ~127; }
    offs[NEXP] = s;
  }
}

__global__ void rowmap_kernel(const int* __restrict__ pair_e, const float* __restrict__ pair_w,
                              const int* __restrict__ pair_pos, const int* __restrict__ offs,
                              int* __restrict__ row_token, float* __restrict__ row_weight,
                              int* __restrict__ tok2row) {
  int p = blockIdx.x * 256 + threadIdx.x;
  if (p >= NPAIR) return;
  int e = pair_e[p];
  int row = offs[e] + pair_pos[p];
  row_token[row] = p >> 1;
  row_weight[row] = pair_w[p];
  tok2row[p] = row;
}

// -------- gather tokens -> compact bf16 A, pre-swizzled by (row&7) --------
__global__ __launch_bounds__(256) void gather_kernel(const float* __restrict__ hs,
                                                     const int* __restrict__ row_token,
                                                     short* __restrict__ A_c) {
  int r = blockIdx.x;
  int tok = row_token[r];
  int t = threadIdx.x;
  if (tok < 0) {           // pad row must be zeros
    *(s16x8*)&A_c[(size_t)r * HDIM + t * 8] = (s16x8)0;
    return;
  }
  const float* src = hs + (size_t)tok * HDIM + t * 8;
  f32x4 v0 = *(const f32x4*)src;
  f32x4 v1 = *(const f32x4*)(src + 4);
  s16x8 o;
#pragma unroll
  for (int j = 0; j < 4; j++) { o[j] = f2bf(v0[j]); o[4 + j] = f2bf(v1[j]); }
  int dstg = (t & ~7) | ((t & 7) ^ (r & 7));
  *(s16x8*)&A_c[(size_t)r * HDIM + dstg * 8] = o;
}

// ===== gate_up GEMM, fused fp32 B: 128M x (64g+64u)N x BK64, 48KB LDS =====
// A: bf16 gload_lds dbuf; B: fp32 reg-prefetch + cvt + conflict-free
// swizzled ds_write (single buffer). All global loads issued inside the
// MFMA region -> full-region latency cover before top-of-loop barrier.
__global__ __launch_bounds__(256, 3) void gateup_kernel(
    const short* __restrict__ A_c, const float* __restrict__ guw,
    const int* __restrict__ offs, short* __restrict__ S) {
  int bid = blockIdx.x;                 // 880 = 8 x 110, XCD-chunked
  int work = (bid & 7) * 110 + (bid >> 3);
  int rblk = work / 22, nb = work % 22;
  int rb = rblk * 128;
  if (rb >= offs[NEXP]) return;
  int e = 0;
#pragma unroll
  for (int i = 1; i < NEXP; i++) e += (rb >= offs[i]);
  const float* Wsrc = guw + (size_t)e * HDIM * NG;
  const short* Ar = A_c + (size_t)rb * HDIM;

  __shared__ short As[2][128 * 64];     // 2 x 16 KB
  __shared__ short Bs[128 * 64];        // 16 KB: n 0-63 gate, 64-127 up
  int tid = threadIdx.x, lane = tid & 63, wid = tid >> 6;
  int wm = wid >> 1, wn = wid & 1;
  int lm = lane & 15, lg = lane >> 4;

  // B staging: thread -> 8 consecutive cols (oct), 4 consecutive k (kq)
  int oct = tid >> 4, kq = tid & 15;
  int n0 = oct * 8;                     // LDS col base 0..120
  int gcol = (oct < 8) ? (nb * 64 + n0) : (IDIM + nb * 64 + (n0 - 64));
  const float* Bp = Wsrc + gcol;

  f32x4 acc[4][4];                      // [mi][nf]; nf 0,1=gate 2,3=up
#pragma unroll
  for (int a = 0; a < 4; a++)
#pragma unroll
    for (int b = 0; b < 4; b++) acc[a][b] = (f32x4)0.f;

  f32x4 va[4], vb[4];                   // B prefetch regs (32 floats)

  auto STAGE_A = [&](int buf, int kt) { // 4 gload_lds per thread
    int k0 = kt * 64;
#pragma unroll
    for (int it = 0; it < 4; it++) {
      int idx = tid + it * 256;
      gload_lds16(Ar + (size_t)(idx >> 3) * HDIM + k0 + (idx & 7) * 8, &As[buf][idx * 8]);
    }
  };
  auto LOAD_B = [&](int kt) {           // 8 global f32x4
    const float* p = Bp + (size_t)(kt * 64 + kq * 4) * NG;
#pragma unroll
    for (int j = 0; j < 4; j++) {
      va[j] = *(const f32x4*)(p + (size_t)j * NG);
      vb[j] = *(const f32x4*)(p + (size_t)j * NG + 4);
    }
  };
  auto WRITE_B = [&]() {                // cvt + transposed swizzled write
    int gc = kq >> 1, half = kq & 1;
#pragma unroll
    for (int i = 0; i < 8; i++) {
      int n = n0 + i;
      s16x4 w;
#pragma unroll
      for (int j = 0; j < 4; j++) w[j] = f2bf(i < 4 ? va[j][i] : vb[j][i - 4]);
      *(s16x4*)&Bs[n * 64 + ((gc ^ (n & 7)) * 8) + half * 4] = w;
    }
  };

  STAGE_A(0, 0);
  LOAD_B(0);
  const int NT = HDIM / 64;             // 32
#pragma unroll 1
  for (int kt = 0; kt < NT; kt++) {
    int cur = kt & 1;
    __syncthreads();                    // A(kt)+B(kt) landed (full-region cover)
    WRITE_B();
    __syncthreads();                    // B visible; no vmem pending -> cheap
    if (kt + 1 < NT) {                  // next tile's loads under this MFMA region
      STAGE_A(cur ^ 1, kt + 1);
      LOAD_B(kt + 1);
    }
#pragma unroll
    for (int ks = 0; ks < 2; ks++) {
      bf16x8 a[4], b[4];
#pragma unroll
      for (int mi = 0; mi < 4; mi++) {
        int m = wm * 64 + mi * 16 + lm;
        a[mi] = *(const bf16x8*)&As[cur][m * 64 + (((ks * 4 + lg) ^ (m & 7)) * 8)];
      }
#pragma unroll
      for (int nf = 0; nf < 4; nf++) {
        int n = (nf >> 1) * 64 + wn * 32 + (nf & 1) * 16 + lm;
        b[nf] = *(const bf16x8*)&Bs[n * 64 + (((ks * 4 + lg) ^ (n & 7)) * 8)];
      }
      __builtin_amdgcn_s_setprio(1);
#pragma unroll
      for (int mi = 0; mi < 4; mi++)
#pragma unroll
        for (int nf = 0; nf < 4; nf++)
          acc[mi][nf] = __builtin_amdgcn_mfma_f32_16x16x32_bf16(a[mi], b[nf], acc[mi][nf], 0, 0, 0);
      __builtin_amdgcn_s_setprio(0);
    }
  }
  // epilogue: SiLU(gate)*up -> S (bf16, granule-swizzled by rg&7 per 64 cols)
#pragma unroll
  for (int mi = 0; mi < 4; mi++)
#pragma unroll
    for (int j = 0; j < 2; j++)
#pragma unroll
      for (int jj = 0; jj < 4; jj++) {
        int row = wm * 64 + mi * 16 + lg * 4 + jj;
        int rg = rb + row;
        int o = wn * 32 + j * 16 + lm;
        int dc = (((o >> 3) ^ (rg & 7)) << 3) | (o & 7);
        float g = acc[mi][j][jj], u = acc[mi][2 + j][jj];
        float sv = (g / (1.f + expf(-g))) * u;
        S[(size_t)rg * IDIM + nb * 64 + dc] = f2bf(sv);
      }
}

// ===== down GEMM, fused fp32 B: 128M x 128N x BK64, 48KB LDS ==============
__global__ __launch_bounds__(256, 3) void down_kernel(
    const short* __restrict__ S, const float* __restrict__ dw,
    const int* __restrict__ offs, short* __restrict__ Sout) {
  int bid = blockIdx.x;                 // 640 = 8 x 80, XCD-chunked
  int work = (bid & 7) * 80 + (bid >> 3);
  int rblk = work / 16, nb = work % 16;
  int rb = rblk * 128;
  if (rb >= offs[NEXP]) return;
  int e = 0;
#pragma unroll
  for (int i = 1; i < NEXP; i++) e += (rb >= offs[i]);
  const float* Wsrc = dw + (size_t)e * IDIM * HDIM;
  const short* Ar = S + (size_t)rb * IDIM;

  __shared__ short As[2][128 * 64];
  __shared__ short Bs[128 * 64];
  int tid = threadIdx.x, lane = tid & 63, wid = tid >> 6;
  int wm = wid >> 1, wn = wid & 1;
  int lm = lane & 15, lg = lane >> 4;

  int oct = tid >> 4, kq = tid & 15;
  int n0 = oct * 8;
  const float* Bp = Wsrc + nb * 128 + n0;

  f32x4 acc[4][4];
#pragma unroll
  for (int a = 0; a < 4; a++)
#pragma unroll
    for (int b = 0; b < 4; b++) acc[a][b] = (f32x4)0.f;

  f32x4 va[4], vb[4];

  auto STAGE_A = [&](int buf, int kt) {
    int k0 = kt * 64;
#pragma unroll
    for (int it = 0; it < 4; it++) {
      int idx = tid + it * 256;
      gload_lds16(Ar + (size_t)(idx >> 3) * IDIM + k0 + (idx & 7) * 8, &As[buf][idx * 8]);
    }
  };
  auto LOAD_B = [&](int kt) {
    const float* p = Bp + (size_t)(kt * 64 + kq * 4) * HDIM;
#pragma unroll
    for (int j = 0; j < 4; j++) {
      va[j] = *(const f32x4*)(p + (size_t)j * HDIM);
      vb[j] = *(const f32x4*)(p + (size_t)j * HDIM + 4);
    }
  };
  auto WRITE_B = [&]() {
    int gc = kq >> 1, half = kq & 1;
#pragma unroll
    for (int i = 0; i < 8; i++) {
      int n = n0 + i;
      s16x4 w;
#pragma unroll
      for (int j = 0; j < 4; j++) w[j] = f2bf(i < 4 ? va[j][i] : vb[j][i - 4]);
      *(s16x4*)&Bs[n * 64 + ((gc ^ (n & 7)) * 8) + half * 4] = w;
    }
  };

  STAGE_A(0, 0);
  LOAD_B(0);
  const int NT = IDIM / 64;             // 22
#pragma unroll 1
  for (int kt = 0; kt < NT; kt++) {
    int cur = kt & 1;
    __syncthreads();
    WRITE_B();
    __syncthreads();
    if (kt + 1 < NT) {
      STAGE_A(cur ^ 1, kt + 1);
      LOAD_B(kt + 1);
    }
#pragma unroll
    for (int ks = 0; ks < 2; ks++) {
      bf16x8 a[4], b[4];
#pragma unroll
      for (int mi = 0; mi < 4; mi++) {
        int m = wm * 64 + mi * 16 + lm;
        a[mi] = *(const bf16x8*)&As[cur][m * 64 + (((ks * 4 + lg) ^ (m & 7)) * 8)];
      }
#pragma unroll
      for (int nf = 0; nf < 4; nf++) {
        int n = wn * 64 + nf * 16 + lm;
        b[nf] = *(const bf16x8*)&Bs[n * 64 + (((ks * 4 + lg) ^ (n & 7)) * 8)];
      }
      __builtin_amdgcn_s_setprio(1);
#pragma unroll
      for (int mi = 0; mi < 4; mi++)
#pragma unroll
        for (int nf = 0; nf < 4; nf++)
          acc[mi][nf] = __builtin_amdgcn_mfma_f32_16x16x32_bf16(a[mi], b[nf], acc[mi][nf], 0, 0, 0);
      __builtin_amdgcn_s_setprio(0);
    }
  }
  // epilogue: plain bf16 stores (combine does the weighted sum)
#pragma unroll
  for (int mi = 0; mi < 4; mi++)
#pragma unroll
    for (int nf = 0; nf < 4; nf++)
#pragma unroll
      for (int jj = 0; jj < 4; jj++) {
        int row = wm * 64 + mi * 16 + lg * 4 + jj;
        int col = nb * 128 + wn * 64 + nf * 16 + lm;
        Sout[(size_t)(rb + row) * HDIM + col] = f2bf(acc[mi][nf][jj]);
      }
}

// ------------- combine: out[t] = w1*Sout[r1] + w2*Sout[r2] ---------------
__global__ __launch_bounds__(256) void combine_kernel(
    const short* __restrict__ Sout, const int* __restrict__ tok2row,
    const float* __restrict__ row_weight, float* __restrict__ out) {
  int t = blockIdx.x;
  int r1 = tok2row[2 * t], r2 = tok2row[2 * t + 1];
  float w1 = row_weight[r1], w2 = row_weight[r2];
  int c = threadIdx.x * 8;
  s16x8 a = *(const s16x8*)&Sout[(size_t)r1 * HDIM + c];
  s16x8 b = *(const s16x8*)&Sout[(size_t)r2 * HDIM + c];
  float* o = out + (size_t)t * HDIM + c;
#pragma unroll
  for (int j = 0; j < 8; j++) o[j] = w1 * bf2f(a[j]) + w2 * bf2f(b[j]);
}

extern "C" void kernel_launch(void* const* d_in, const int* in_sizes, int n_in,
                              void* d_out, int out_size, void* d_ws, size_t ws_size,
                              hipStream_t stream) {
  const float* hs  = (const float*)d_in[0];
  const float* rw  = (const float*)d_in[1];
  const float* guw = (const float*)d_in[2];
  const float* dw  = (const float*)d_in[3];
  float* out = (float*)d_out;

  char* ws = (char*)d_ws;
  size_t off = 0;
  auto take = [&](size_t b) { size_t p = off; off = (off + b + 255) & ~(size_t)255; return p; };
  size_t s_off      = take((size_t)RPAD * IDIM * 2);   // 14.4 MB
  int*   counts     = (int*)(ws + take(32 * 4));
  int*   offs       = (int*)(ws + take(16 * 4));
  int*   pair_e     = (int*)(ws + take(NPAIR * 4));
  float* pair_w     = (float*)(ws + take(NPAIR * 4));
  int*   pair_pos   = (int*)(ws + take(NPAIR * 4));
  int*   row_token  = (int*)(ws + take(RPAD * 4));
  float* row_weight = (float*)(ws + take(RPAD * 4));
  int*   tok2row    = (int*)(ws + take(NPAIR * 4));
  size_t ac_off     = take((size_t)RPAD * HDIM * 2);   // 21.0 MB
  size_t sout_off   = take((size_t)RPAD * HDIM * 2);   // 21.0 MB

  short* S    = (short*)(ws + s_off);
  short* A_c  = (short*)(ws + ac_off);
  short* Sout = (short*)(ws + sout_off);

  hipMemsetAsync(counts, 0, 32 * 4, stream);
  hipMemsetAsync(row_token, 0xFF, RPAD * 4, stream);

  router_kernel<<<T_TOK / 4, 256, 0, stream>>>(hs, rw, pair_e, pair_w, pair_pos, counts);
  prefix_kernel<<<1, 64, 0, stream>>>(counts, offs);
  rowmap_kernel<<<NPAIR / 256, 256, 0, stream>>>(pair_e, pair_w, pair_pos, offs,
                                                 row_token, row_weight, tok2row);
  gather_kernel<<<RPAD, 256, 0, stream>>>(hs, row_token, A_c);

  gateup_kernel<<<880, 256, 0, stream>>>(A_c, guw, offs, S);
  down_kernel<<<640, 256, 0, stream>>>(S, dw, offs, Sout);
  combine_kernel<<<T_TOK, 256, 0, stream>>>(Sout, tok2row, row_weight, out);
}

// Round 11
// 284.946 us; speedup vs baseline: 1.2020x; 1.2020x over previous
//
#include <hip/hip_runtime.h>
#include <hip/hip_bf16.h>
#include <math.h>

#define T_TOK 2048
#define HDIM  2048
#define IDIM  1408
#define NG    2816          // 2*IDIM
#define NEXP  8
#define NPAIR (T_TOK*2)
#define RPAD  6144          // 4096 rows + per-expert pad-to-256 (max 6136)
#define DW_GRANULES (NEXP*HDIM*(IDIM/8))   // 2,883,584
#define CVT_Q 11264                        // per-block granule quota (32*352)

typedef __attribute__((ext_vector_type(4))) float  f32x4;
typedef __attribute__((ext_vector_type(4))) short  s16x4;
typedef __attribute__((ext_vector_type(8))) short  s16x8;
typedef __attribute__((ext_vector_type(8))) __bf16 bf16x8;

__device__ __forceinline__ short f2bf(float f) {
  union { float f; unsigned u; } v; v.f = f;
  unsigned r = v.u + 0x7FFFu + ((v.u >> 16) & 1u);   // RNE
  return (short)(r >> 16);
}

__device__ __forceinline__ float bf2f(short s) {
  union { unsigned u; float f; } v; v.u = ((unsigned)(unsigned short)s) << 16;
  return v.f;
}

__device__ __forceinline__ void gload_lds16(const void* g, void* l) {
  __builtin_amdgcn_global_load_lds((const __attribute__((address_space(1))) unsigned int*)g,
                                   (__attribute__((address_space(3))) unsigned int*)l,
                                   16, 0, 0);
}

// ---------------- router ----------------
__global__ void router_kernel(const float* __restrict__ hs, const float* __restrict__ rw,
                              int* __restrict__ pair_e, float* __restrict__ pair_w,
                              int* __restrict__ pair_pos, int* __restrict__ counts) {
  int wid = threadIdx.x >> 6, lane = threadIdx.x & 63;
  int t = blockIdx.x * 4 + wid;
  float acc[NEXP];
#pragma unroll
  for (int e = 0; e < NEXP; e++) acc[e] = 0.f;
  const float* h = hs + (size_t)t * HDIM;
  for (int k = lane; k < HDIM; k += 64) {
    float x = h[k];
    f32x4 w0 = *(const f32x4*)(rw + (size_t)k * NEXP);
    f32x4 w1 = *(const f32x4*)(rw + (size_t)k * NEXP + 4);
#pragma unroll
    for (int e = 0; e < 4; e++) { acc[e] += x * w0[e]; acc[e + 4] += x * w1[e]; }
  }
#pragma unroll
  for (int e = 0; e < NEXP; e++)
#pragma unroll
    for (int off = 32; off > 0; off >>= 1)
      acc[e] += __shfl_xor(acc[e], off, 64);
  if (lane == 0) {
    int i1 = 0; float v1 = acc[0];
#pragma unroll
    for (int e = 1; e < NEXP; e++) if (acc[e] > v1) { v1 = acc[e]; i1 = e; }
    int i2 = -1; float v2 = -3.4e38f;
#pragma unroll
    for (int e = 0; e < NEXP; e++) if (e != i1 && acc[e] > v2) { v2 = acc[e]; i2 = e; }
    float w2 = 1.f / (1.f + expf(v1 - v2));
    float w1 = 1.f - w2;
    int p1 = atomicAdd(&counts[i1], 1);
    int p2 = atomicAdd(&counts[i2], 1);
    pair_e[2*t]   = i1; pair_w[2*t]   = w1; pair_pos[2*t]   = p1;
    pair_e[2*t+1] = i2; pair_w[2*t+1] = w2; pair_pos[2*t+1] = p2;
  }
}

__global__ void prefix_kernel(const int* __restrict__ counts, int* __restrict__ offs) {
  if (threadIdx.x == 0) {
    int s = 0;
    for (int e = 0; e < NEXP; e++) { offs[e] = s; s += (counts[e] + 255) & ~255; }
    offs[NEXP] = s;
  }
}

__global__ void rowmap_kernel(const int* __restrict__ pair_e, const float* __restrict__ pair_w,
                              const int* __restrict__ pair_pos, const int* __restrict__ offs,
                              int* __restrict__ row_token, float* __restrict__ row_weight,
                              int* __restrict__ tok2row) {
  int p = blockIdx.x * 256 + threadIdx.x;
  if (p >= NPAIR) return;
  int e = pair_e[p];
  int row = offs[e] + pair_pos[p];
  row_token[row] = p >> 1;
  row_weight[row] = pair_w[p];
  tok2row[p] = row;
}

// -------- gather tokens -> compact bf16 A, pre-swizzled by (row&7) --------
__global__ __launch_bounds__(256) void gather_kernel(const float* __restrict__ hs,
                                                     const int* __restrict__ row_token,
                                                     short* __restrict__ A_c) {
  int r = blockIdx.x;
  int tok = row_token[r];
  int t = threadIdx.x;
  if (tok < 0) {           // pad row must be zeros
    *(s16x8*)&A_c[(size_t)r * HDIM + t * 8] = (s16x8)0;
    return;
  }
  const float* src = hs + (size_t)tok * HDIM + t * 8;
  f32x4 v0 = *(const f32x4*)src;
  f32x4 v1 = *(const f32x4*)(src + 4);
  s16x8 o;
#pragma unroll
  for (int j = 0; j < 4; j++) { o[j] = f2bf(v0[j]); o[4 + j] = f2bf(v1[j]); }
  int dstg = (t & ~7) | ((t & 7) ^ (r & 7));
  *(s16x8*)&A_c[(size_t)r * HDIM + dstg * 8] = o;
}

// ===== gate_up GEMM (fp32 W direct) + EMBEDDED dw->Wd bf16 convert =========
// 256M x (128g+128u)N x BK64, 512 thr, 96KB LDS (r7 structure, measured 135us).
// Embedded convert rides the latency bubbles: loads issued top-of-iter
// (before STAGE_A so vmcnt(12) excludes them), store at MFMA-region end.
__global__ __launch_bounds__(512, 2) void gateup_kernel(
    const short* __restrict__ A_c, const float* __restrict__ guw,
    const float* __restrict__ dwsrc, const int* __restrict__ offs,
    short* __restrict__ S, short* __restrict__ Wd) {
  int nb = blockIdx.x;                  // 0..10
  int rb = blockIdx.y * 256;
  int bid = blockIdx.y * 11 + nb;       // 0..263
  int tid = threadIdx.x;

  // ---- embedded convert state ----
  float cf[8];
  int cvt_h = 0, cvt_gk = 0, cvt_e = 0, cvt_ok = 0;
  auto CVT_LOAD = [&](int kt) {
    cvt_ok = 0;
    if (tid < 352) {
      int gid = bid * CVT_Q + kt * 352 + tid;
      if (gid < DW_GRANULES) {
        cvt_ok = 1;
        cvt_h = gid & (HDIM - 1);
        int rest = gid >> 11;
        cvt_gk = rest % (IDIM / 8);
        cvt_e = rest / (IDIM / 8);
        const float* sp = dwsrc + ((size_t)cvt_e * IDIM + cvt_gk * 8) * HDIM + cvt_h;
#pragma unroll
        for (int j = 0; j < 8; j++) cf[j] = sp[(size_t)j * HDIM];
      }
    }
  };
  auto CVT_STORE = [&]() {
    if (cvt_ok) {
      int slot = (cvt_gk & ~7) | ((cvt_gk ^ cvt_h) & 7);
      s16x8 o;
#pragma unroll
      for (int j = 0; j < 8; j++) o[j] = f2bf(cf[j]);
      *(s16x8*)&Wd[((size_t)cvt_e * HDIM + cvt_h) * IDIM + slot * 8] = o;
    }
  };

  bool active = (rb < offs[NEXP]);
  if (!active) {                        // idle CU: still must do convert quota
    for (int kt = 0; kt < 32; kt++) { CVT_LOAD(kt); CVT_STORE(); }
    return;
  }
  int e = 0;
#pragma unroll
  for (int i = 1; i < NEXP; i++) e += (rb >= offs[i]);
  const float* Wsrc = guw + (size_t)e * HDIM * NG;
  const short* Ar = A_c + (size_t)rb * HDIM;

  __shared__ short bufA[2][256 * 64];   // 2 x 32 KB
  __shared__ short bufB[256 * 64];      // 32 KB: n 0-127 gate, 128-255 up
  int lane = tid & 63, wid = tid >> 6;
  int wm = wid >> 2, wn = wid & 3;
  int lm = lane & 15, lg = lane >> 4;

  // B staging map: thread -> 8 consecutive n (oct), 4 consecutive k (kq)
  int oct = tid >> 4, kq = tid & 15;
  int n0 = oct * 8;
  int col = (n0 < 128) ? (nb * 128 + n0) : (IDIM + nb * 128 + (n0 - 128));
  const float* Bp = Wsrc + col;

  f32x4 acc[8][4];                      // [mi][nf]; nf 0,1=gate 2,3=up
#pragma unroll
  for (int a = 0; a < 8; a++)
#pragma unroll
    for (int b = 0; b < 4; b++) acc[a][b] = (f32x4)0.f;

  f32x4 va[4], vb[4];                   // B prefetch regs (32 floats)

  auto STAGE_A = [&](int buf, int kt) { // 4 gload_lds per thread
    int k0 = kt * 64;
#pragma unroll
    for (int it = 0; it < 4; it++) {
      int idx = tid + it * 512;
      gload_lds16(Ar + (size_t)(idx >> 3) * HDIM + k0 + (idx & 7) * 8, &bufA[buf][idx * 8]);
    }
  };
  auto LOAD_B = [&](int kt) {           // 8 global f32x4
    const float* p = Bp + (size_t)(kt * 64 + kq * 4) * NG;
#pragma unroll
    for (int j = 0; j < 4; j++) {
      va[j] = *(const f32x4*)(p + (size_t)j * NG);
      vb[j] = *(const f32x4*)(p + (size_t)j * NG + 4);
    }
  };
  auto WRITE_B = [&]() {                // cvt + transposed swizzled write
    int gc = kq >> 1, half = kq & 1;
#pragma unroll
    for (int i = 0; i < 8; i++) {
      int n = n0 + i;
      s16x4 w;
#pragma unroll
      for (int j = 0; j < 4; j++) w[j] = f2bf(i < 4 ? va[j][i] : vb[j][i - 4]);
      *(s16x4*)&bufB[n * 64 + ((gc ^ (n & 7)) * 8) + half * 4] = w;
    }
  };
  auto MFMA_KS = [&](int cur, int ks) {
    bf16x8 a[8], b[4];
#pragma unroll
    for (int mi = 0; mi < 8; mi++) {
      int m = wm * 128 + mi * 16 + lm;
      a[mi] = *(const bf16x8*)&bufA[cur][m * 64 + (((ks * 4 + lg) ^ (m & 7)) * 8)];
    }
#pragma unroll
    for (int nf = 0; nf < 4; nf++) {
      int n = (nf >> 1) * 128 + wn * 32 + (nf & 1) * 16 + lm;
      b[nf] = *(const bf16x8*)&bufB[n * 64 + (((ks * 4 + lg) ^ (n & 7)) * 8)];
    }
    __builtin_amdgcn_s_setprio(1);
#pragma unroll
    for (int mi = 0; mi < 8; mi++)
#pragma unroll
      for (int nf = 0; nf < 4; nf++)
        acc[mi][nf] = __builtin_amdgcn_mfma_f32_16x16x32_bf16(a[mi], b[nf], acc[mi][nf], 0, 0, 0);
    __builtin_amdgcn_s_setprio(0);
  };

  STAGE_A(0, 0);                        // A(0): 4 gload_lds
  LOAD_B(0);                            // B(0): 8 loads
  const int NT = HDIM / 64;             // 32
#pragma unroll 1
  for (int kt = 0; kt < NT; kt++) {
    int cur = kt & 1;
    CVT_LOAD(kt);                       // 8 scalar loads, issued FIRST
    if (kt + 1 < NT) {
      STAGE_A(cur ^ 1, kt + 1);
      // newest 12 = {8 cvt loads + 4 STAGE_A(kt+1)}; waits A(kt)+B(kt)
      asm volatile("s_waitcnt vmcnt(12)" ::: "memory");
    } else {
      asm volatile("s_waitcnt vmcnt(0)" ::: "memory");
    }
    WRITE_B();
    if (kt + 1 < NT) LOAD_B(kt + 1);    // in flight across both barriers
    asm volatile("s_waitcnt lgkmcnt(0)" ::: "memory");
    __builtin_amdgcn_s_barrier();       // staging visible to all waves
    MFMA_KS(cur, 0);
    MFMA_KS(cur, 1);
    CVT_STORE();                        // compiler-counted wait keeps LOAD_B in flight
    asm volatile("s_waitcnt lgkmcnt(0)" ::: "memory");
    __builtin_amdgcn_s_barrier();       // reads retired; buffers free
  }
  // epilogue: SiLU(gate)*up -> S (bf16, granule-swizzled by rg&7 per 64 cols)
#pragma unroll
  for (int mi = 0; mi < 8; mi++)
#pragma unroll
    for (int nfg = 0; nfg < 2; nfg++)
#pragma unroll
      for (int j = 0; j < 4; j++) {
        int row = wm * 128 + mi * 16 + lg * 4 + j;
        int rg = rb + row;
        int scol = nb * 128 + wn * 32 + nfg * 16 + lm;
        int base = scol & ~63, o = scol & 63;
        int dc = (((o >> 3) ^ (rg & 7)) << 3) | (o & 7);
        float g = acc[mi][nfg][j], u = acc[mi][nfg + 2][j];
        float sv = (g / (1.f + expf(-g))) * u;
        S[(size_t)rg * IDIM + base + dc] = f2bf(sv);
      }
}

// ===== down GEMM: m97-style, 128M x 128N x BK64, 32KB LDS, bf16 Wd ========
__global__ __launch_bounds__(256) void down_kernel(
    const short* __restrict__ S, const short* __restrict__ Wd,
    const int* __restrict__ offs, short* __restrict__ Sout) {
  int bid = blockIdx.x;                 // 768 = 8 x 96, XCD-chunked
  int work = (bid & 7) * 96 + (bid >> 3);
  int rblk = work / 16, nb = work % 16;
  int rb = rblk * 128;
  if (rb >= offs[NEXP]) return;
  int e = 0;
#pragma unroll
  for (int i = 1; i < NEXP; i++) e += (rb >= offs[i]);
  const short* Ar = S + (size_t)rb * IDIM;
  const short* Bw = Wd + ((size_t)e * HDIM + nb * 128) * IDIM;

  __shared__ short As[128 * 64];        // 16 KB
  __shared__ short Bs[128 * 64];        // 16 KB
  int tid = threadIdx.x, lane = tid & 63, wid = tid >> 6;
  int wm = wid >> 1, wn = wid & 1;
  int lm = lane & 15, lg = lane >> 4;

  f32x4 acc[4][4];
#pragma unroll
  for (int a = 0; a < 4; a++)
#pragma unroll
    for (int b = 0; b < 4; b++) acc[a][b] = (f32x4)0.f;

  for (int kt = 0; kt < IDIM / 64; kt++) {   // 22 steps
    int k0 = kt * 64;
    __syncthreads();
#pragma unroll
    for (int it = 0; it < 4; it++) {
      int idx = tid + it * 256;
      gload_lds16(Ar + (size_t)(idx >> 3) * IDIM + k0 + (idx & 7) * 8, &As[idx * 8]);
      gload_lds16(Bw + (size_t)(idx >> 3) * IDIM + k0 + (idx & 7) * 8, &Bs[idx * 8]);
    }
    __syncthreads();
#pragma unroll
    for (int ks = 0; ks < 2; ks++) {
      bf16x8 a[4], b[4];
#pragma unroll
      for (int mi = 0; mi < 4; mi++) {
        int m = wm * 64 + mi * 16 + lm;
        a[mi] = *(const bf16x8*)&As[m * 64 + (((ks * 4 + lg) ^ (m & 7)) * 8)];
      }
#pragma unroll
      for (int nf = 0; nf < 4; nf++) {
        int n = wn * 64 + nf * 16 + lm;
        b[nf] = *(const bf16x8*)&Bs[n * 64 + (((ks * 4 + lg) ^ (n & 7)) * 8)];
      }
#pragma unroll
      for (int mi = 0; mi < 4; mi++)
#pragma unroll
        for (int nf = 0; nf < 4; nf++)
          acc[mi][nf] = __builtin_amdgcn_mfma_f32_16x16x32_bf16(a[mi], b[nf], acc[mi][nf], 0, 0, 0);
    }
  }
#pragma unroll
  for (int mi = 0; mi < 4; mi++)
#pragma unroll
    for (int nf = 0; nf < 4; nf++)
#pragma unroll
      for (int jj = 0; jj < 4; jj++) {
        int row = wm * 64 + mi * 16 + lg * 4 + jj;
        int col = nb * 128 + wn * 64 + nf * 16 + lm;
        Sout[(size_t)(rb + row) * HDIM + col] = f2bf(acc[mi][nf][jj]);
      }
}

// ------------- combine: out[t] = w1*Sout[r1] + w2*Sout[r2] ---------------
__global__ __launch_bounds__(256) void combine_kernel(
    const short* __restrict__ Sout, const int* __restrict__ tok2row,
    const float* __restrict__ row_weight, float* __restrict__ out) {
  int t = blockIdx.x;
  int r1 = tok2row[2 * t], r2 = tok2row[2 * t + 1];
  float w1 = row_weight[r1], w2 = row_weight[r2];
  int c = threadIdx.x * 8;
  s16x8 a = *(const s16x8*)&Sout[(size_t)r1 * HDIM + c];
  s16x8 b = *(const s16x8*)&Sout[(size_t)r2 * HDIM + c];
  float* o = out + (size_t)t * HDIM + c;
#pragma unroll
  for (int j = 0; j < 8; j++) o[j] = w1 * bf2f(a[j]) + w2 * bf2f(b[j]);
}

extern "C" void kernel_launch(void* const* d_in, const int* in_sizes, int n_in,
                              void* d_out, int out_size, void* d_ws, size_t ws_size,
                              hipStream_t stream) {
  const float* hs  = (const float*)d_in[0];
  const float* rw  = (const float*)d_in[1];
  const float* guw = (const float*)d_in[2];
  const float* dw  = (const float*)d_in[3];
  float* out = (float*)d_out;

  char* ws = (char*)d_ws;
  size_t off = 0;
  auto take = [&](size_t b) { size_t p = off; off = (off + b + 255) & ~(size_t)255; return p; };
  size_t s_off      = take((size_t)RPAD * IDIM * 2);   // 17.3 MB
  int*   counts     = (int*)(ws + take(32 * 4));
  int*   offs       = (int*)(ws + take(16 * 4));
  int*   pair_e     = (int*)(ws + take(NPAIR * 4));
  float* pair_w     = (float*)(ws + take(NPAIR * 4));
  int*   pair_pos   = (int*)(ws + take(NPAIR * 4));
  int*   row_token  = (int*)(ws + take(RPAD * 4));
  float* row_weight = (float*)(ws + take(RPAD * 4));
  int*   tok2row    = (int*)(ws + take(NPAIR * 4));
  size_t ac_off     = take((size_t)RPAD * HDIM * 2);   // 25.2 MB
  size_t sout_off   = take((size_t)RPAD * HDIM * 2);   // 25.2 MB
  size_t wd_off     = take((size_t)NEXP * HDIM * IDIM * 2);  // 46.1 MB

  short* S    = (short*)(ws + s_off);
  short* A_c  = (short*)(ws + ac_off);
  short* Sout = (short*)(ws + sout_off);
  short* Wd   = (short*)(ws + wd_off);

  hipMemsetAsync(counts, 0, 32 * 4, stream);
  hipMemsetAsync(row_token, 0xFF, RPAD * 4, stream);

  router_kernel<<<T_TOK / 4, 256, 0, stream>>>(hs, rw, pair_e, pair_w, pair_pos, counts);
  prefix_kernel<<<1, 64, 0, stream>>>(counts, offs);
  rowmap_kernel<<<NPAIR / 256, 256, 0, stream>>>(pair_e, pair_w, pair_pos, offs,
                                                 row_token, row_weight, tok2row);
  gather_kernel<<<RPAD, 256, 0, stream>>>(hs, row_token, A_c);

  gateup_kernel<<<dim3(11, RPAD / 256), 512, 0, stream>>>(A_c, guw, dw, offs, S, Wd);
  down_kernel<<<768, 256, 0, stream>>>(S, Wd, offs, Sout);
  combine_kernel<<<T_TOK, 256, 0, stream>>>(Sout, tok2row, row_weight, out);
}